// Round 4
// baseline (459.870 us; speedup 1.0000x reference)
//
#include <hip/hip_runtime.h>

typedef unsigned short u16;
typedef unsigned int   u32;
typedef __attribute__((ext_vector_type(8))) short bf16x8;   // 8 bf16 (4 VGPRs)
typedef __attribute__((ext_vector_type(4))) float f32x4;    // mfma acc

#define EPS 1e-5f
#define MFMA(a,b,c) __builtin_amdgcn_mfma_f32_16x16x32_bf16(a,b,c,0,0,0)

// ---- wbuf (fp32) element offsets ----
constexpr int OB_b1=0, OB_g1=64, OB_be1=128, OB_b2=192, OB_bm1=256, OB_w192=320,
              OB_bm2=384, OB_gn=448, OB_bn=512, OB_bg1=576, OB_bg2=640,
              OB_Wg1=704, OB_Wg2=8896, WB_TOT=12992;
// ---- frag buffer (u16/bf16) element offsets ----
constexpr int FR_Wm1=0;          // 24 frags (K=192) = 12288
constexpr int FR_Wm2=12288;      // 8 frags  (K=64)  = 4096
constexpr int FR_rel=16384;      // 7 rows x 80 (pad) = 560, alloc 576
constexpr int FR_W1 =16960;      // 32 frags (K=256) = 16384
constexpr int FR_W2 =33344;      // 8 frags  (K=64)  = 4096
constexpr int FR_TOT=37440;

__device__ __forceinline__ float bf2f(u32 u) { return __uint_as_float(u << 16); }
__device__ __forceinline__ u16 f2bf(float f) {
  u32 b = __float_as_uint(f);
  return (u16)((b + 0x7fffu + ((b >> 16) & 1u)) >> 16);  // RNE
}
__device__ __forceinline__ u32 fkey(float f) {  // monotone float->u32 (finite)
  u32 b = __float_as_uint(f);
  return (b & 0x80000000u) ? ~b : (b | 0x80000000u);
}

// ---- prep: weights->wbuf/frags; plus dst histogram for counting sort ----
__launch_bounds__(256)
__global__ void k_prep(const float* __restrict__ W1, const float* __restrict__ b1,
                       const float* __restrict__ g1, const float* __restrict__ be1,
                       const float* __restrict__ W2, const float* __restrict__ b2,
                       const float* __restrict__ rel_emb,
                       const float* __restrict__ Wm1, const float* __restrict__ bm1,
                       const float* __restrict__ Wm2, const float* __restrict__ bm2,
                       const float* __restrict__ gn, const float* __restrict__ bn,
                       const float* __restrict__ Wg1, const float* __restrict__ bg1,
                       const float* __restrict__ Wg2, const float* __restrict__ bg2,
                       float* __restrict__ wbuf, u16* __restrict__ frags,
                       const float* __restrict__ te, u32* __restrict__ counts,
                       int E, int N) {
  int tid = blockIdx.x * 256 + threadIdx.x;
  int nth = gridDim.x * 256;
  for (int i = tid; i < 64; i += nth) {
    wbuf[OB_b1 + i] = b1[i];   wbuf[OB_g1 + i] = g1[i];
    wbuf[OB_be1 + i] = be1[i]; wbuf[OB_b2 + i] = b2[i];
    wbuf[OB_bm1 + i] = bm1[i]; wbuf[OB_w192 + i] = Wm1[192 * 64 + i];
    wbuf[OB_bm2 + i] = bm2[i]; wbuf[OB_gn + i] = gn[i];
    wbuf[OB_bn + i] = bn[i];   wbuf[OB_bg1 + i] = bg1[i];
    wbuf[OB_bg2 + i] = bg2[i];
  }
  for (int i = tid; i < 8192; i += nth) wbuf[OB_Wg1 + i] = Wg1[i];
  for (int i = tid; i < 4096; i += nth) wbuf[OB_Wg2 + i] = Wg2[i];
  for (int idx = tid; idx < 16384; idx += nth) {
    int f = idx >> 9, L = (idx >> 3) & 63, j = idx & 7;
    int k = (f >> 2) * 32 + ((L >> 4) << 3) + j, n = ((f & 3) << 4) + (L & 15);
    frags[FR_W1 + idx] = f2bf(W1[k * 64 + n]);
  }
  for (int idx = tid; idx < 4096; idx += nth) {
    int f = idx >> 9, L = (idx >> 3) & 63, j = idx & 7;
    int k = (f >> 2) * 32 + ((L >> 4) << 3) + j, n = ((f & 3) << 4) + (L & 15);
    frags[FR_W2 + idx] = f2bf(W2[k * 64 + n]);
  }
  for (int idx = tid; idx < 12288; idx += nth) {
    int f = idx >> 9, L = (idx >> 3) & 63, j = idx & 7;
    int k = (f >> 2) * 32 + ((L >> 4) << 3) + j, n = ((f & 3) << 4) + (L & 15);
    frags[FR_Wm1 + idx] = f2bf(Wm1[k * 64 + n]);
  }
  for (int idx = tid; idx < 4096; idx += nth) {
    int f = idx >> 9, L = (idx >> 3) & 63, j = idx & 7;
    int k = (f >> 2) * 32 + ((L >> 4) << 3) + j, n = ((f & 3) << 4) + (L & 15);
    frags[FR_Wm2 + idx] = f2bf(Wm2[k * 64 + n]);
  }
  for (int idx = tid; idx < 576; idx += nth) {
    int r = idx / 80, c = idx % 80;
    frags[FR_rel + idx] = (r < 7 && c < 64) ? f2bf(rel_emb[r * 64 + c]) : (u16)0;
  }
  // dst histogram
  for (int e = tid; e < E; e += nth) {
    float dv = te[(size_t)e * 4 + 1];
    int d = min(max((int)dv, 0), N - 1);
    atomicAdd(&counts[d], 1u);
  }
}

// ---- scan step 1: per-1024-chunk sums ----
__launch_bounds__(256)
__global__ void k_scan1(const u32* __restrict__ counts, u32* __restrict__ partial, int M) {
  __shared__ u32 red[256];
  int base = blockIdx.x * 1024;
  u32 s = 0;
  #pragma unroll
  for (int k = 0; k < 4; k++) { int i = base + threadIdx.x + k * 256; if (i < M) s += counts[i]; }
  red[threadIdx.x] = s; __syncthreads();
  for (int off = 128; off > 0; off >>= 1) {
    if (threadIdx.x < (u32)off) red[threadIdx.x] += red[threadIdx.x + off];
    __syncthreads();
  }
  if (threadIdx.x == 0) partial[blockIdx.x] = red[0];
}

// ---- scan step 2: exclusive scan of chunk sums (PB <= 1024) ----
__launch_bounds__(256)
__global__ void k_scan2(u32* __restrict__ partial, int PB) {
  __shared__ u32 sh[1024];
  for (int i = threadIdx.x; i < PB; i += 256) sh[i] = partial[i];
  __syncthreads();
  if (threadIdx.x == 0) {
    u32 acc = 0;
    for (int i = 0; i < PB; i++) { u32 t = sh[i]; sh[i] = acc; acc += t; }
  }
  __syncthreads();
  for (int i = threadIdx.x; i < PB; i += 256) partial[i] = sh[i];
}

// ---- scan step 3: full exclusive offsets + cursor copy ----
__launch_bounds__(256)
__global__ void k_scan3(const u32* __restrict__ counts, const u32* __restrict__ partial,
                        u32* __restrict__ offsets, u32* __restrict__ cursor, int M) {
  __shared__ u32 tsum[256];
  int base = blockIdx.x * 1024 + threadIdx.x * 4;
  u32 c[4]; u32 s = 0;
  #pragma unroll
  for (int k = 0; k < 4; k++) { int i = base + k; c[k] = (i < M) ? counts[i] : 0u; s += c[k]; }
  tsum[threadIdx.x] = s; __syncthreads();
  for (int off = 1; off < 256; off <<= 1) {
    u32 v = (threadIdx.x >= (u32)off) ? tsum[threadIdx.x - off] : 0u;
    __syncthreads();
    tsum[threadIdx.x] += v;
    __syncthreads();
  }
  u32 excl = (threadIdx.x == 0) ? 0u : tsum[threadIdx.x - 1];
  u32 run = partial[blockIdx.x] + excl;
  #pragma unroll
  for (int k = 0; k < 4; k++) {
    int i = base + k;
    if (i < M) { offsets[i] = run; cursor[i] = run; run += c[k]; }
  }
}

// ---- build CSR permutation: perm[slot] = edge id ----
__launch_bounds__(256)
__global__ void k_perm(const float* __restrict__ te, u32* __restrict__ cursor,
                       u32* __restrict__ perm, int E, int N) {
  int tid = blockIdx.x * 256 + threadIdx.x;
  int nth = gridDim.x * 256;
  for (int e = tid; e < E; e += nth) {
    float dv = te[(size_t)e * 4 + 1];
    int d = min(max((int)dv, 0), N - 1);
    u32 pos = atomicAdd(&cursor[d], 1u);
    perm[pos] = (u32)e;
  }
}

// ---- stage A (MFMA): h = relu(relu(LN(X@W1+b1)) @ W2 + b2) -> bf16 ----
__launch_bounds__(256, 3)
__global__ void k_h(const float* __restrict__ X, const float* __restrict__ wbuf,
                    const u16* __restrict__ frags, u16* __restrict__ hb, int N) {
  __shared__ __align__(16) u16 sW1[32 * 512];
  __shared__ __align__(16) u16 sW2[8 * 512];
  __shared__ __align__(16) u16 st[4][16 * 72];

  {
    const uint4* srcp = (const uint4*)(frags + FR_W1);
    uint4* d1 = (uint4*)sW1;
    for (int i = threadIdx.x; i < 2048; i += 256) d1[i] = srcp[i];
    const uint4* srcp2 = (const uint4*)(frags + FR_W2);
    uint4* d2 = (uint4*)sW2;
    for (int i = threadIdx.x; i < 512; i += 256) d2[i] = srcp2[i];
  }
  __syncthreads();

  int lane = threadIdx.x & 63, wave = threadIdx.x >> 6;
  int m = lane & 15, quad = lane >> 4, koff = quad * 8, col0 = m;

  float b1v[4], g1v[4], be1v[4], b2v[4];
  #pragma unroll
  for (int nt = 0; nt < 4; nt++) {
    int c = nt * 16 + col0;
    b1v[nt] = wbuf[OB_b1 + c]; g1v[nt] = wbuf[OB_g1 + c];
    be1v[nt] = wbuf[OB_be1 + c]; b2v[nt] = wbuf[OB_b2 + c];
  }

  int ntiles = (N + 15) / 16;
  int wid = blockIdx.x * 4 + wave, nw = gridDim.x * 4;
  for (int tile = wid; tile < ntiles; tile += nw) {
    int n0 = tile * 16;
    int nm = min(n0 + m, N - 1);
    const float* xr = X + (size_t)nm * 256 + koff;

    f32x4 acc[4] = {};
    #pragma unroll 4
    for (int ks = 0; ks < 8; ks++) {
      float4 u0 = *(const float4*)(xr + ks * 32);
      float4 u1 = *(const float4*)(xr + ks * 32 + 4);
      bf16x8 a;
      a[0] = (short)f2bf(u0.x); a[1] = (short)f2bf(u0.y);
      a[2] = (short)f2bf(u0.z); a[3] = (short)f2bf(u0.w);
      a[4] = (short)f2bf(u1.x); a[5] = (short)f2bf(u1.y);
      a[6] = (short)f2bf(u1.z); a[7] = (short)f2bf(u1.w);
      #pragma unroll
      for (int nt = 0; nt < 4; nt++) {
        bf16x8 b = *(const bf16x8*)(sW1 + (ks * 4 + nt) * 512 + lane * 8);
        acc[nt] = MFMA(a, b, acc[nt]);
      }
    }

    float v[4][4];
    #pragma unroll
    for (int nt = 0; nt < 4; nt++)
      #pragma unroll
      for (int r = 0; r < 4; r++) v[nt][r] = acc[nt][r] + b1v[nt];

    #pragma unroll
    for (int r = 0; r < 4; r++) {
      float s = v[0][r] + v[1][r] + v[2][r] + v[3][r];
      #pragma unroll
      for (int mk = 8; mk >= 1; mk >>= 1) s += __shfl_xor(s, mk, 64);
      float mu = s * (1.f / 64.f);
      float q = 0.f;
      #pragma unroll
      for (int nt = 0; nt < 4; nt++) { float d = v[nt][r] - mu; q += d * d; }
      #pragma unroll
      for (int mk = 8; mk >= 1; mk >>= 1) q += __shfl_xor(q, mk, 64);
      float rs = rsqrtf(q * (1.f / 64.f) + EPS);
      #pragma unroll
      for (int nt = 0; nt < 4; nt++) {
        float h1 = fmaxf(fmaf((v[nt][r] - mu) * rs, g1v[nt], be1v[nt]), 0.f);
        st[wave][(quad * 4 + r) * 72 + nt * 16 + col0] = f2bf(h1);
      }
    }
    __builtin_amdgcn_wave_barrier();

    f32x4 acc2[4] = {};
    #pragma unroll
    for (int ks = 0; ks < 2; ks++) {
      bf16x8 a2 = *(const bf16x8*)(st[wave] + m * 72 + ks * 32 + koff);
      #pragma unroll
      for (int nt = 0; nt < 4; nt++) {
        bf16x8 b = *(const bf16x8*)(sW2 + (ks * 4 + nt) * 512 + lane * 8);
        acc2[nt] = MFMA(a2, b, acc2[nt]);
      }
    }
    __builtin_amdgcn_wave_barrier();

    #pragma unroll
    for (int nt = 0; nt < 4; nt++)
      #pragma unroll
      for (int r = 0; r < 4; r++) {
        int row = n0 + quad * 4 + r;
        if (row < N)
          hb[(size_t)row * 64 + nt * 16 + col0] = f2bf(fmaxf(acc2[nt][r] + b2v[nt], 0.f));
      }
  }
}

// ---- stage B+C (MFMA, CSR order): edge MLP + segmented reduce, few atomics ----
// Each wave owns a contiguous range of 128 CSR positions (8 tiles of 16).
// dst is non-decreasing within the range; interior dst groups -> plain stores,
// range-border groups -> atomicAdd.
__launch_bounds__(256, 3)
__global__ void k_edge(const float* __restrict__ te, const u32* __restrict__ perm,
                       const u16* __restrict__ hb, const float* __restrict__ wbuf,
                       const u16* __restrict__ frags, float* __restrict__ agg,
                       int E, int N, int nranges) {
  __shared__ __align__(16) u16 sWm1[24 * 512];
  __shared__ __align__(16) u16 sWm2[8 * 512];
  __shared__ __align__(16) u16 srel[576];
  __shared__ __align__(16) u16 st[4][16 * 72];
  __shared__ int ldst[4][16];

  {
    const uint4* s1 = (const uint4*)(frags + FR_Wm1);
    uint4* d1 = (uint4*)sWm1;
    for (int i = threadIdx.x; i < 1536; i += 256) d1[i] = s1[i];
    const uint4* s2 = (const uint4*)(frags + FR_Wm2);
    uint4* d2 = (uint4*)sWm2;
    for (int i = threadIdx.x; i < 512; i += 256) d2[i] = s2[i];
    const uint4* s3 = (const uint4*)(frags + FR_rel);
    uint4* d3 = (uint4*)srel;
    for (int i = threadIdx.x; i < 72; i += 256) d3[i] = s3[i];
  }
  __syncthreads();

  int lane = threadIdx.x & 63, wave = threadIdx.x >> 6;
  int m = lane & 15, quad = lane >> 4, koff = quad * 8, col0 = m;

  float bm1v[4], w192v[4], bm2v[4];
  #pragma unroll
  for (int nt = 0; nt < 4; nt++) {
    int c = nt * 16 + col0;
    bm1v[nt] = wbuf[OB_bm1 + c];
    w192v[nt] = wbuf[OB_w192 + c];
    bm2v[nt] = wbuf[OB_bm2 + c];
  }

  int wid = blockIdx.x * 4 + wave, nw = gridDim.x * 4;
  for (int range = wid; range < nranges; range += nw) {
    int r0 = range * 128;
    int run_dst = -2;       // current run's dst (-2 = none)
    float run = 0.f;        // per-lane partial sum for column `lane`
    bool bs = false;        // run started at range start?

    #pragma unroll 1
    for (int t8 = 0; t8 < 8; t8++) {
      int p0 = r0 + t8 * 16;
      if (p0 >= E) break;

      int src = 0, dstc = 0, rel = 0, dtag = -1; float w = 0.f;
      if (lane < 16) {
        int p = p0 + lane;
        if (p < E) {
          u32 eid = perm[p];
          float4 v = *(const float4*)(te + (size_t)eid * 4);
          src = min(max((int)v.x, 0), N - 1);
          dstc = min(max((int)v.y, 0), N - 1);
          rel = min(max((int)v.z, 0), 6);
          w = v.w;
          dtag = dstc;
        }
        ldst[wave][lane] = dtag;
      }
      int src_m = __shfl(src, m, 64);
      int dst_m = __shfl(dstc, m, 64);
      int rel_m = __shfl(rel, m, 64);

      const u16* hs = hb + (size_t)src_m * 64;
      const u16* hd = hb + (size_t)dst_m * 64;
      bf16x8 af[6];
      af[0] = *(const bf16x8*)(hs + koff);
      af[1] = *(const bf16x8*)(hs + 32 + koff);
      af[2] = *(const bf16x8*)(hd + koff);
      af[3] = *(const bf16x8*)(hd + 32 + koff);
      af[4] = *(const bf16x8*)(srel + rel_m * 80 + koff);
      af[5] = *(const bf16x8*)(srel + rel_m * 80 + 32 + koff);

      f32x4 acc[4] = {};
      #pragma unroll
      for (int ks = 0; ks < 6; ks++) {
        #pragma unroll
        for (int nt = 0; nt < 4; nt++) {
          bf16x8 b = *(const bf16x8*)(sWm1 + (ks * 4 + nt) * 512 + lane * 8);
          acc[nt] = MFMA(af[ks], b, acc[nt]);
        }
      }

      // epilogue 1: + bm1 + w*Wm1[192], relu, t -> LDS bf16
      float wrow[4];
      #pragma unroll
      for (int r = 0; r < 4; r++) wrow[r] = __shfl(w, quad * 4 + r, 64);
      #pragma unroll
      for (int nt = 0; nt < 4; nt++)
        #pragma unroll
        for (int r = 0; r < 4; r++) {
          float v = fmaf(wrow[r], w192v[nt], acc[nt][r] + bm1v[nt]);
          st[wave][(quad * 4 + r) * 72 + nt * 16 + col0] = f2bf(fmaxf(v, 0.f));
        }
      __builtin_amdgcn_wave_barrier();

      f32x4 acc2[4] = {};
      #pragma unroll
      for (int ks = 0; ks < 2; ks++) {
        bf16x8 a2 = *(const bf16x8*)(st[wave] + m * 72 + ks * 32 + koff);
        #pragma unroll
        for (int nt = 0; nt < 4; nt++) {
          bf16x8 b = *(const bf16x8*)(sWm2 + (ks * 4 + nt) * 512 + lane * 8);
          acc2[nt] = MFMA(a2, b, acc2[nt]);
        }
      }
      __builtin_amdgcn_wave_barrier();

      // write message rows (+bm2) back to st (bf16), row-major
      #pragma unroll
      for (int nt = 0; nt < 4; nt++)
        #pragma unroll
        for (int r = 0; r < 4; r++)
          st[wave][(quad * 4 + r) * 72 + nt * 16 + col0] =
              f2bf(acc2[nt][r] + bm2v[nt]);
      __builtin_amdgcn_wave_barrier();

      // segmented reduce over the 16 rows; column = lane
      #pragma unroll 1
      for (int r = 0; r < 16; r++) {
        int d = ldst[wave][r];                       // uniform broadcast
        float val = bf2f(st[wave][r * 72 + lane]);
        if (d != run_dst) {
          if (run_dst >= 0) {
            float* ap = agg + (size_t)run_dst * 64 + lane;
            if (bs) atomicAdd(ap, run); else *ap = run;
          }
          run_dst = d; run = val; bs = (t8 == 0 && r == 0);
        } else {
          run += val;
        }
      }
      __builtin_amdgcn_wave_barrier();
    }
    // final flush: run may continue into the next range -> atomic
    if (run_dst >= 0) atomicAdd(agg + (size_t)run_dst * 64 + lane, run);
  }
}

// ---- stage D1: nodes = LN(h+agg); global column sum + max ----
__launch_bounds__(256)
__global__ void k_nodes(const u16* __restrict__ hb, const float* __restrict__ agg,
                        const float* __restrict__ wbuf, float* __restrict__ gsum,
                        u32* __restrict__ gmax, int N) {
  int lane = threadIdx.x & 63, wave = threadIdx.x >> 6;
  int wid = blockIdx.x * 4 + wave;
  int nw = gridDim.x * 4;
  float gn = wbuf[OB_gn + lane], bn = wbuf[OB_bn + lane];
  float sj = 0.f, mj = -3.0e38f;
  for (int n = wid; n < N; n += nw) {
    float v = bf2f(hb[(size_t)n * 64 + lane]) + agg[(size_t)n * 64 + lane];
    float s = v;
    #pragma unroll
    for (int m = 32; m >= 1; m >>= 1) s += __shfl_xor(s, m, 64);
    float mu = s * (1.f / 64.f);
    float d = v - mu;
    float q = d * d;
    #pragma unroll
    for (int m = 32; m >= 1; m >>= 1) q += __shfl_xor(q, m, 64);
    float rs = rsqrtf(q * (1.f / 64.f) + EPS);
    float val = fmaf(d * rs, gn, bn);
    sj += val;
    mj = fmaxf(mj, val);
  }
  __shared__ float bs[256], bm[256];
  bs[threadIdx.x] = sj;
  bm[threadIdx.x] = mj;
  __syncthreads();
  if (threadIdx.x < 64) {
    int t = threadIdx.x;
    float ts = bs[t] + bs[64 + t] + bs[128 + t] + bs[192 + t];
    float tm = fmaxf(fmaxf(bm[t], bm[64 + t]), fmaxf(bm[128 + t], bm[192 + t]));
    atomicAdd(gsum + t, ts);
    atomicMax(gmax + t, fkey(tm));
  }
}

// ---- stage D2: g=[mean,max]; out = relu(g@Wg1+bg1)@Wg2+bg2 (fp32 out) ----
__launch_bounds__(128)
__global__ void k_final(const float* __restrict__ wbuf, const float* __restrict__ gsum,
                        const u32* __restrict__ gmax, float* __restrict__ out, int N) {
  __shared__ float g[128];
  __shared__ float y1[64];
  int t = threadIdx.x;
  if (t < 64) {
    g[t] = gsum[t] / (float)N;
  } else {
    u32 k = gmax[t - 64];
    u32 b = (k & 0x80000000u) ? (k & 0x7fffffffu) : ~k;
    g[t] = __uint_as_float(b);
  }
  __syncthreads();
  if (t < 64) {
    float a = wbuf[OB_bg1 + t];
    for (int i = 0; i < 128; i++) a = fmaf(g[i], wbuf[OB_Wg1 + i * 64 + t], a);
    y1[t] = fmaxf(a, 0.f);
  }
  __syncthreads();
  if (t < 64) {
    float a = wbuf[OB_bg2 + t];
    for (int k = 0; k < 64; k++) a = fmaf(y1[k], wbuf[OB_Wg2 + k * 64 + t], a);
    out[t] = a;
  }
}

extern "C" void kernel_launch(void* const* d_in, const int* in_sizes, int n_in,
                              void* d_out, int out_size, void* d_ws, size_t ws_size,
                              hipStream_t stream) {
  const int N = in_sizes[0] / 256;
  const int E = in_sizes[1] / 4;
  const int M = N + 1;                 // scan length (offsets[N] = E)
  const int Mp = (M + 63) & ~63;
  const int PB = (M + 1023) / 1024;

  char* ws = (char*)d_ws;
  float* agg    = (float*)ws;                          // N*64 f32
  float* gsum   = agg + (size_t)N * 64;                // 64
  u32*   gmax   = (u32*)(gsum + 64);                   // 64
  u32*   counts = gmax + 64;                           // Mp
  size_t zeroB  = (size_t)N * 64 * 4 + 512 + (size_t)Mp * 4;
  u32*   offsets = counts + Mp;                        // Mp
  u32*   cursor  = offsets + Mp;                       // Mp
  u32*   partial = cursor + Mp;                        // 256
  u32*   perm    = partial + 256;                      // E
  u16*   hb      = (u16*)(perm + ((E + 7) & ~7));      // N*64 bf16
  float* wbuf    = (float*)(hb + (size_t)N * 64);      // WB_TOT f32
  u16*   frags   = (u16*)(wbuf + WB_TOT);              // FR_TOT u16

  const float* X  = (const float*)d_in[0];
  const float* te = (const float*)d_in[1];

  hipMemsetAsync(agg, 0, zeroB, stream);
  hipLaunchKernelGGL(k_prep, dim3(400), dim3(256), 0, stream,
                     (const float*)d_in[2], (const float*)d_in[3], (const float*)d_in[4],
                     (const float*)d_in[5], (const float*)d_in[6], (const float*)d_in[7],
                     (const float*)d_in[8], (const float*)d_in[9], (const float*)d_in[10],
                     (const float*)d_in[11], (const float*)d_in[12], (const float*)d_in[13],
                     (const float*)d_in[14], (const float*)d_in[15], (const float*)d_in[16],
                     (const float*)d_in[17], (const float*)d_in[18], wbuf, frags,
                     te, counts, E, N);
  hipLaunchKernelGGL(k_scan1, dim3(PB), dim3(256), 0, stream, counts, partial, M);
  hipLaunchKernelGGL(k_scan2, dim3(1), dim3(256), 0, stream, partial, PB);
  hipLaunchKernelGGL(k_scan3, dim3(PB), dim3(256), 0, stream, counts, partial, offsets, cursor, M);
  hipLaunchKernelGGL(k_perm, dim3(800), dim3(256), 0, stream, te, cursor, perm, E, N);
  hipLaunchKernelGGL(k_h, dim3(800), dim3(256), 0, stream, X, wbuf, frags, hb, N);
  int nranges = (E + 127) / 128;
  hipLaunchKernelGGL(k_edge, dim3(768), dim3(256), 0, stream,
                     te, perm, hb, wbuf, frags, agg, E, N, nranges);
  hipLaunchKernelGGL(k_nodes, dim3(2048), dim3(256), 0, stream, hb, agg, wbuf, gsum, gmax, N);
  hipLaunchKernelGGL(k_final, dim3(1), dim3(128), 0, stream, wbuf, gsum, gmax, (float*)d_out, N);
}